// Round 2
// baseline (7205.347 us; speedup 1.0000x reference)
//
#include <hip/hip_runtime.h>

#define Bn 256
#define Tn 512
#define Vn 64
#define Hn 256
#define INn 129

typedef __fp16 half2_t __attribute__((ext_vector_type(2)));

static __device__ __forceinline__ unsigned int cvt2(float a, float b) {
  return __builtin_bit_cast(unsigned int, __builtin_amdgcn_cvt_pkrtz(a, b));
}

static __device__ __forceinline__ float dot2(unsigned int w, unsigned int x, float acc) {
#if __has_builtin(__builtin_amdgcn_fdot2)
  return __builtin_amdgcn_fdot2(__builtin_bit_cast(half2_t, w),
                                __builtin_bit_cast(half2_t, x), acc, false);
#else
  half2_t a = __builtin_bit_cast(half2_t, w);
  half2_t b = __builtin_bit_cast(half2_t, x);
  return acc + (float)a.x * (float)b.x + (float)a.y * (float)b.y;
#endif
}

static __device__ __forceinline__ float xor1_add(float v) {
  int i = __builtin_bit_cast(int, v);
  int j = __builtin_amdgcn_ds_swizzle(i, 0x041F);  // xor lane^1
  return v + __builtin_bit_cast(float, j);
}

static __device__ __forceinline__ float fast_exp2(float x) {
#if __has_builtin(__builtin_amdgcn_exp2f)
  return __builtin_amdgcn_exp2f(x);
#else
  return exp2f(x);
#endif
}
static __device__ __forceinline__ float fast_rcp(float x) {
#if __has_builtin(__builtin_amdgcn_rcpf)
  return __builtin_amdgcn_rcpf(x);
#else
  return 1.f / x;
#endif
}
static __device__ __forceinline__ float sigmoid_f(float x) {
  return fast_rcp(1.f + fast_exp2(-1.44269504f * x));
}
static __device__ __forceinline__ float tanh_f(float x) {
  // tanh(x) = 1 - 2/(exp(2x)+1); exp(2x) = exp2(2.885390x). Saturates correctly at +/-inf.
  return 1.f - 2.f * fast_rcp(1.f + fast_exp2(2.88539008f * x));
}

// LDS layout (bytes):
//   zn_chunks : [16][512] uint4   = 131072   (c 0..7: z-row chunks, 8..15: n-row chunks; per-thread swizzled)
//   zn_tail   : [512] uint2       =   4096   (.x = z tail pair, .y = n tail pair)
//   x_buf     : [2][2][36] uint   =    576   (ping-pong, per-ks slice of 33 data uints + pad; 16B-aligned slices)
//   h_buf     : [2][256] f16      =   1024   (ping-pong hidden state)
//   t_lds     : [512] float       =   2048
#define SMEM_BYTES 138816

__global__ __launch_bounds__(512, 2)
void gru_scan_kernel(const float* __restrict__ times_in,
                     const float* __restrict__ data_in,
                     const float* __restrict__ mask_in,
                     const float* __restrict__ W_ih,
                     const float* __restrict__ W_hh,
                     const float* __restrict__ b_ih,
                     const float* __restrict__ b_hh,
                     float* __restrict__ out) {
  extern __shared__ char smem[];
  uint4* zn_chunks = (uint4*)(smem);
  uint2* zn_tail = (uint2*)(smem + 131072);
  unsigned int* x_buf = (unsigned int*)(smem + 135168);
  __fp16* h_buf = (__fp16*)(smem + 135744);
  float* t_lds = (float*)(smem + 136768);

  const int tid = threadIdx.x;
  const int b = blockIdx.x;
  const int jg = tid >> 1;  // hidden index this thread owns
  const int ks = tid & 1;   // k-split half
  const int cb = ks * 66;   // starting column of this thread's ih k-slice (padded IN=132)

  // ---- init: times row ----
  t_lds[tid] = times_in[(size_t)b * Tn + tid];

  // ---- init: register-resident weights (f16 pairs packed in uints) ----
  unsigned int whr[64], whz[64], whn[64], wir[33];
  {
    const float* w0 = W_hh + (size_t)jg * Hn + ks * 128;
    const float* w1 = W_hh + (size_t)(jg + 256) * Hn + ks * 128;
    const float* w2 = W_hh + (size_t)(jg + 512) * Hn + ks * 128;
#pragma unroll
    for (int c = 0; c < 64; ++c) {
      whr[c] = cvt2(w0[2 * c], w0[2 * c + 1]);
      whz[c] = cvt2(w1[2 * c], w1[2 * c + 1]);
      whn[c] = cvt2(w2[2 * c], w2[2 * c + 1]);
    }
    const float* wi = W_ih + (size_t)jg * INn;
#pragma unroll
    for (int c = 0; c < 33; ++c) {
      int col = cb + 2 * c;
      float f0 = (col < INn) ? wi[col] : 0.f;
      float f1 = (col + 1 < INn) ? wi[col + 1] : 0.f;
      wir[c] = cvt2(f0, f1);
    }
  }

  // ---- init: LDS-resident W_ih z/n rows, per-thread swizzled chunk layout ----
  {
    const float* wz = W_ih + (size_t)(256 + jg) * INn;
    const float* wn = W_ih + (size_t)(512 + jg) * INn;
#pragma unroll
    for (int c = 0; c < 8; ++c) {
      unsigned int uz[4], un[4];
#pragma unroll
      for (int q = 0; q < 4; ++q) {
        int col = cb + c * 8 + q * 2;
        float z0 = (col < INn) ? wz[col] : 0.f;
        float z1 = (col + 1 < INn) ? wz[col + 1] : 0.f;
        float n0 = (col < INn) ? wn[col] : 0.f;
        float n1 = (col + 1 < INn) ? wn[col + 1] : 0.f;
        uz[q] = cvt2(z0, z1);
        un[q] = cvt2(n0, n1);
      }
      zn_chunks[c * 512 + tid] = make_uint4(uz[0], uz[1], uz[2], uz[3]);
      zn_chunks[(8 + c) * 512 + tid] = make_uint4(un[0], un[1], un[2], un[3]);
    }
    int colt = cb + 64;
    float z0 = (colt < INn) ? wz[colt] : 0.f;
    float z1 = (colt + 1 < INn) ? wz[colt + 1] : 0.f;
    float n0 = (colt < INn) ? wn[colt] : 0.f;
    float n1 = (colt + 1 < INn) ? wn[colt + 1] : 0.f;
    zn_tail[tid] = make_uint2(cvt2(z0, z1), cvt2(n0, n1));
  }

  // ---- init: biases (r,z fold both; n keeps ih/hh separate because n=tanh(xn + r*hn)) ----
  const float br = b_ih[jg] + b_hh[jg];
  const float bz = b_ih[jg + 256] + b_hh[jg + 256];
  const float bxn = b_ih[jg + 512];
  const float bhn = b_hh[jg + 512];

  // ---- init: h=0, x pads, x(0) ----
  if (tid < 256) h_buf[tid] = (__fp16)0.f;
  if (tid >= 256 && tid < 258) {  // zero col 129 (half 135) in both buffers
    int buf = tid - 256;
    ((__fp16*)(x_buf + buf * 72))[135] = (__fp16)0.f;
  }
  if (tid >= 258 && tid < 260) {  // zero cols 130,131 (slice1 uint 32) in both buffers
    int buf = tid - 258;
    x_buf[buf * 72 + 36 + 32] = 0u;
  }
  if (tid < 128) {  // x(0): cols 0..63 data, 64..127 mask
    float v = (tid < 64) ? data_in[((size_t)b * Tn) * Vn + tid]
                         : mask_in[((size_t)b * Tn) * Vn + (tid - 64)];
    __fp16* xh = (__fp16*)(x_buf);
    int hi = (tid < 66) ? tid : (72 + tid - 66);
    xh[hi] = (__fp16)v;
  } else if (tid == 128) {  // delta(0) = t[1]-t[0]  (col 128 -> half 134)
    float d0 = times_in[(size_t)b * Tn + 1] - times_in[(size_t)b * Tn + 0];
    ((__fp16*)(x_buf))[134] = (__fp16)d0;
  }
  __syncthreads();

  // ---- sequential scan ----
  float hcur = 0.f;
  int cur = 0;
  for (int t = 0; t < Tn; ++t) {
    const int nxt = cur ^ 1;

    // prefetch x(t+1) from global early; latency hidden under the dot phase
    const int tn = (t < Tn - 1) ? (t + 1) : (Tn - 1);
    float pf = 0.f;
    if (tid < 64) pf = data_in[((size_t)b * Tn + tn) * Vn + tid];
    else if (tid < 128) pf = mask_in[((size_t)b * Tn + tn) * Vn + (tid - 64)];

    float sr = 0.f, sz = 0.f, sxn = 0.f, shn = 0.f;

    // hh dots: register weights x LDS h slice (broadcast reads)
    {
      const uint4* hb = (const uint4*)(h_buf + cur * 256 + ks * 128);
#pragma unroll
      for (int c = 0; c < 16; ++c) {
        uint4 hv = hb[c];
        sr = dot2(whr[4 * c + 0], hv.x, sr);
        sz = dot2(whz[4 * c + 0], hv.x, sz);
        shn = dot2(whn[4 * c + 0], hv.x, shn);
        sr = dot2(whr[4 * c + 1], hv.y, sr);
        sz = dot2(whz[4 * c + 1], hv.y, sz);
        shn = dot2(whn[4 * c + 1], hv.y, shn);
        sr = dot2(whr[4 * c + 2], hv.z, sr);
        sz = dot2(whz[4 * c + 2], hv.z, sz);
        shn = dot2(whn[4 * c + 2], hv.z, shn);
        sr = dot2(whr[4 * c + 3], hv.w, sr);
        sz = dot2(whz[4 * c + 3], hv.w, sz);
        shn = dot2(whn[4 * c + 3], hv.w, shn);
      }
    }
    // ih dots: r from registers, z/n streamed from swizzled LDS
    {
      const uint4* xb = (const uint4*)(x_buf + cur * 72 + ks * 36);
#pragma unroll
      for (int c = 0; c < 8; ++c) {
        uint4 xv = xb[c];
        uint4 wz4 = zn_chunks[c * 512 + tid];
        uint4 wn4 = zn_chunks[(8 + c) * 512 + tid];
        sr = dot2(wir[4 * c + 0], xv.x, sr);
        sz = dot2(wz4.x, xv.x, sz);
        sxn = dot2(wn4.x, xv.x, sxn);
        sr = dot2(wir[4 * c + 1], xv.y, sr);
        sz = dot2(wz4.y, xv.y, sz);
        sxn = dot2(wn4.y, xv.y, sxn);
        sr = dot2(wir[4 * c + 2], xv.z, sr);
        sz = dot2(wz4.z, xv.z, sz);
        sxn = dot2(wn4.z, xv.z, sxn);
        sr = dot2(wir[4 * c + 3], xv.w, sr);
        sz = dot2(wz4.w, xv.w, sz);
        sxn = dot2(wn4.w, xv.w, sxn);
      }
      unsigned int xt = x_buf[cur * 72 + ks * 36 + 32];
      uint2 tl = zn_tail[tid];
      sr = dot2(wir[32], xt, sr);
      sz = dot2(tl.x, xt, sz);
      sxn = dot2(tl.y, xt, sxn);
    }

    // reduce the two k-halves (lanes 2i <-> 2i+1)
    sr = xor1_add(sr);
    sz = xor1_add(sz);
    sxn = xor1_add(sxn);
    shn = xor1_add(shn);

    // gates + masked state update (both parity lanes compute identically)
    float r = sigmoid_f(sr + br);
    float z = sigmoid_f(sz + bz);
    float n = tanh_f(sxn + bxn + r * (shn + bhn));
    float hN = (1.f - z) * n + z * hcur;
    float mt = t_lds[t];
    hcur = (mt > 0.f) ? hN : hcur;

    // publish h(t+1) and x(t+1) into the other buffer; single barrier per step
    if (ks == 0) h_buf[nxt * 256 + jg] = (__fp16)hcur;
    if (tid < 128) {
      __fp16* xh = (__fp16*)(x_buf + nxt * 72);
      int hi = (tid < 66) ? tid : (72 + tid - 66);
      xh[hi] = (__fp16)pf;
    } else if (tid == 128) {
      float d = (tn < Tn - 1) ? (t_lds[tn + 1] - t_lds[tn]) : 0.f;
      ((__fp16*)(x_buf + nxt * 72))[134] = (__fp16)d;
    }
    __syncthreads();
    cur = nxt;
  }

  if (ks == 0) out[(size_t)b * Hn + jg] = hcur;
}

extern "C" void kernel_launch(void* const* d_in, const int* in_sizes, int n_in,
                              void* d_out, int out_size, void* d_ws, size_t ws_size,
                              hipStream_t stream) {
  const float* times_in = (const float*)d_in[0];
  const float* data_in = (const float*)d_in[1];
  const float* mask_in = (const float*)d_in[2];
  const float* W_ih = (const float*)d_in[3];
  const float* W_hh = (const float*)d_in[4];
  const float* b_ih = (const float*)d_in[5];
  const float* b_hh = (const float*)d_in[6];
  float* out = (float*)d_out;

  // >64KB dynamic LDS requires explicit opt-in (idempotent host call; graph-capture safe)
  (void)hipFuncSetAttribute(reinterpret_cast<const void*>(gru_scan_kernel),
                            hipFuncAttributeMaxDynamicSharedMemorySize, SMEM_BYTES);

  hipLaunchKernelGGL(gru_scan_kernel, dim3(Bn), dim3(512), SMEM_BYTES, stream,
                     times_in, data_in, mask_in, W_ih, W_hh, b_ih, b_hh, out);
}

// Round 3
// 1264.036 us; speedup vs baseline: 5.7003x; 5.7003x over previous
//
#include <hip/hip_runtime.h>

#define Bn 256
#define Tn 512
#define Vn 64
#define Hn 256
#define INn 129
#define Cc 8                 // timesteps per chunk
#define NCH (Tn / Cc)        // 64 chunks
#define WU 68                // packed uints per W_ih row (132 f16 cols, 16B-aligned)
#define WSZ (768 * WU)       // workspace uints for packed W_ih

typedef __fp16 half2_t __attribute__((ext_vector_type(2)));

static __device__ __forceinline__ unsigned int cvt2(float a, float b) {
  return __builtin_bit_cast(unsigned int, __builtin_amdgcn_cvt_pkrtz(a, b));
}

static __device__ __forceinline__ float dot2(unsigned int w, unsigned int x, float acc) {
#if __has_builtin(__builtin_amdgcn_fdot2)
  return __builtin_amdgcn_fdot2(__builtin_bit_cast(half2_t, w),
                                __builtin_bit_cast(half2_t, x), acc, false);
#else
  half2_t a = __builtin_bit_cast(half2_t, w);
  half2_t b = __builtin_bit_cast(half2_t, x);
  return acc + (float)a.x * (float)b.x + (float)a.y * (float)b.y;
#endif
}

static __device__ __forceinline__ float xor1_add(float v) {
  int i = __builtin_bit_cast(int, v);
  int j = __builtin_amdgcn_ds_swizzle(i, 0x041F);  // xor lane^1
  return v + __builtin_bit_cast(float, j);
}

static __device__ __forceinline__ float fast_exp2(float x) {
#if __has_builtin(__builtin_amdgcn_exp2f)
  return __builtin_amdgcn_exp2f(x);
#else
  return exp2f(x);
#endif
}
static __device__ __forceinline__ float fast_rcp(float x) {
#if __has_builtin(__builtin_amdgcn_rcpf)
  return __builtin_amdgcn_rcpf(x);
#else
  return 1.f / x;
#endif
}
static __device__ __forceinline__ float sigmoid_f(float x) {
  return fast_rcp(1.f + fast_exp2(-1.44269504f * x));
}
static __device__ __forceinline__ float tanh_f(float x) {
  return 1.f - 2.f * fast_rcp(1.f + fast_exp2(2.88539008f * x));
}

// Pack W_ih (768x129 f32) into [768][68] f16-pair uints in workspace.
__global__ void convert_wih(const float* __restrict__ W_ih, unsigned int* __restrict__ w16) {
  int idx = blockIdx.x * 256 + threadIdx.x;
  if (idx >= WSZ) return;
  int j = idx / WU, c = idx - j * WU;
  int col = 2 * c;
  float f0 = (col < INn) ? W_ih[(size_t)j * INn + col] : 0.f;
  float f1 = (col + 1 < INn) ? W_ih[(size_t)j * INn + col + 1] : 0.f;
  w16[idx] = cvt2(f0, f1);
}

// One pass of phase A: dot of W_ih row `col` with all Cc x-vectors in LDS.
template <bool USE_WS>
static __device__ __forceinline__ void phaseA_pass(int col, const unsigned int* __restrict__ w16,
                                                   const float* __restrict__ W_ih,
                                                   const unsigned int* x_lds, float* a) {
  const uint4* wp = (const uint4*)(w16) + (size_t)col * (WU / 4);
  const float* wf = W_ih + (size_t)col * INn;
#pragma unroll 2
  for (int kp = 0; kp < 8; ++kp) {
    uint4 wa, wb;
    if constexpr (USE_WS) {
      wa = wp[2 * kp];
      wb = wp[2 * kp + 1];
    } else {
      const float* f = wf + 16 * kp;
      wa.x = cvt2(f[0], f[1]);   wa.y = cvt2(f[2], f[3]);
      wa.z = cvt2(f[4], f[5]);   wa.w = cvt2(f[6], f[7]);
      wb.x = cvt2(f[8], f[9]);   wb.y = cvt2(f[10], f[11]);
      wb.z = cvt2(f[12], f[13]); wb.w = cvt2(f[14], f[15]);
    }
#pragma unroll
    for (int t = 0; t < Cc; ++t) {
      const uint4* xp = (const uint4*)&x_lds[t * WU + kp * 8];
      uint4 xa = xp[0], xb = xp[1];
      a[t] = dot2(wa.x, xa.x, a[t]);
      a[t] = dot2(wa.y, xa.y, a[t]);
      a[t] = dot2(wa.z, xa.z, a[t]);
      a[t] = dot2(wa.w, xa.w, a[t]);
      a[t] = dot2(wb.x, xb.x, a[t]);
      a[t] = dot2(wb.y, xb.y, a[t]);
      a[t] = dot2(wb.z, xb.z, a[t]);
      a[t] = dot2(wb.w, xb.w, a[t]);
    }
  }
  uint4 wt;
  if constexpr (USE_WS) {
    wt = wp[16];
  } else {
    wt.x = cvt2(wf[128], 0.f); wt.y = 0u; wt.z = 0u; wt.w = 0u;
  }
#pragma unroll
  for (int t = 0; t < Cc; ++t) {
    uint4 xt = *(const uint4*)&x_lds[t * WU + 64];
    a[t] = dot2(wt.x, xt.x, a[t]);
    a[t] = dot2(wt.y, xt.y, a[t]);
  }
}

template <bool USE_WS>
__global__ __launch_bounds__(512, 2)
void gru_scan_kernel(const float* __restrict__ times_in,
                     const float* __restrict__ data_in,
                     const float* __restrict__ mask_in,
                     const unsigned int* __restrict__ w16,
                     const float* __restrict__ W_ih,
                     const float* __restrict__ W_hh,
                     const float* __restrict__ b_ih,
                     const float* __restrict__ b_hh,
                     float* __restrict__ out) {
  __shared__ __align__(16) float gx_lds[Cc * 768];        // 24576 B
  __shared__ __align__(16) unsigned int x_lds[Cc * WU];   //  2176 B
  __shared__ __align__(16) __fp16 h_buf[2 * Hn];          //  1024 B
  __shared__ __align__(16) float t_lds[Tn];               //  2048 B

  const int tid = threadIdx.x;
  const int b = blockIdx.x;
  const int jg = tid >> 1;  // hidden index this thread owns
  const int ks = tid & 1;   // k-split half of the hh dot

  t_lds[tid] = times_in[(size_t)b * Tn + tid];

  // Register-resident W_hh (f16 pairs; 192 uints/thread, the ONLY big array)
  unsigned int whr[64], whz[64], whn[64];
  {
    const float* w0 = W_hh + (size_t)jg * Hn + ks * 128;
    const float* w1 = W_hh + (size_t)(jg + 256) * Hn + ks * 128;
    const float* w2 = W_hh + (size_t)(jg + 512) * Hn + ks * 128;
#pragma unroll
    for (int c = 0; c < 64; ++c) {
      whr[c] = cvt2(w0[2 * c], w0[2 * c + 1]);
      whz[c] = cvt2(w1[2 * c], w1[2 * c + 1]);
      whn[c] = cvt2(w2[2 * c], w2[2 * c + 1]);
    }
  }
  const float brh = b_hh[jg];
  const float bzh = b_hh[jg + 256];
  const float bhn = b_hh[jg + 512];
  const float bi1 = b_ih[tid];
  const float bi2 = (tid < 256) ? b_ih[512 + tid] : 0.f;

  h_buf[tid] = (__fp16)0.f;  // zero both ping-pong h buffers (512 entries)
  __syncthreads();

  float hcur = 0.f;
  int cur = 0;
#pragma unroll 1
  for (int ch = 0; ch < NCH; ++ch) {
    const int t0 = ch * Cc;

    // ---- stage X chunk into LDS as f16 pairs: [t][c] c<64 data/mask, c=64.. delta+pad ----
    {
      int t = tid >> 6;   // 0..7
      int c = tid & 63;   // pair index
      const float* src = (c < 32)
          ? data_in + ((size_t)b * Tn + t0 + t) * Vn + 2 * c
          : mask_in + ((size_t)b * Tn + t0 + t) * Vn + 2 * (c - 32);
      float2 v = *(const float2*)src;
      x_lds[t * WU + c] = cvt2(v.x, v.y);
      if (tid < Cc) {
        int g = t0 + tid;
        float d = (g < Tn - 1) ? (t_lds[g + 1] - t_lds[g]) : 0.f;
        uint4 tl;
        tl.x = cvt2(d, 0.f); tl.y = 0u; tl.z = 0u; tl.w = 0u;
        *(uint4*)&x_lds[tid * WU + 64] = tl;
      }
    }
    __syncthreads();

    // ---- phase A: gx[t][col] = W_ih[col] . x[t] + b_ih[col]  (W streamed from L2) ----
    {
      float a[Cc];
#pragma unroll
      for (int t = 0; t < Cc; ++t) a[t] = bi1;
      phaseA_pass<USE_WS>(tid, w16, W_ih, x_lds, a);
#pragma unroll
      for (int t = 0; t < Cc; ++t) gx_lds[t * 768 + tid] = a[t];
      if (tid < 256) {
#pragma unroll
        for (int t = 0; t < Cc; ++t) a[t] = bi2;
        phaseA_pass<USE_WS>(512 + tid, w16, W_ih, x_lds, a);
#pragma unroll
        for (int t = 0; t < Cc; ++t) gx_lds[t * 768 + 512 + tid] = a[t];
      }
    }
    __syncthreads();

    // ---- phase B: 8 sequential GRU steps (register W_hh dots only) ----
    for (int tt = 0; tt < Cc; ++tt) {
      float sr = 0.f, sz = 0.f, shn = 0.f;
      const uint4* hb = (const uint4*)(h_buf + cur * Hn + ks * 128);
#pragma unroll
      for (int c = 0; c < 16; ++c) {
        uint4 hv = hb[c];
        sr = dot2(whr[4 * c + 0], hv.x, sr);
        sz = dot2(whz[4 * c + 0], hv.x, sz);
        shn = dot2(whn[4 * c + 0], hv.x, shn);
        sr = dot2(whr[4 * c + 1], hv.y, sr);
        sz = dot2(whz[4 * c + 1], hv.y, sz);
        shn = dot2(whn[4 * c + 1], hv.y, shn);
        sr = dot2(whr[4 * c + 2], hv.z, sr);
        sz = dot2(whz[4 * c + 2], hv.z, sz);
        shn = dot2(whn[4 * c + 2], hv.z, shn);
        sr = dot2(whr[4 * c + 3], hv.w, sr);
        sz = dot2(whz[4 * c + 3], hv.w, sz);
        shn = dot2(whn[4 * c + 3], hv.w, shn);
      }
      float gxr = gx_lds[tt * 768 + jg];
      float gxz = gx_lds[tt * 768 + 256 + jg];
      float gxn = gx_lds[tt * 768 + 512 + jg];
      sr = xor1_add(sr);
      sz = xor1_add(sz);
      shn = xor1_add(shn);
      float r = sigmoid_f(gxr + sr + brh);
      float z = sigmoid_f(gxz + sz + bzh);
      float n = tanh_f(gxn + r * (shn + bhn));
      float hN = (1.f - z) * n + z * hcur;
      hcur = (t_lds[t0 + tt] > 0.f) ? hN : hcur;
      if (ks == 0) h_buf[(cur ^ 1) * Hn + jg] = (__fp16)hcur;
      __syncthreads();
      cur ^= 1;
    }
  }

  if (ks == 0) out[(size_t)b * Hn + jg] = hcur;
}

extern "C" void kernel_launch(void* const* d_in, const int* in_sizes, int n_in,
                              void* d_out, int out_size, void* d_ws, size_t ws_size,
                              hipStream_t stream) {
  const float* times_in = (const float*)d_in[0];
  const float* data_in = (const float*)d_in[1];
  const float* mask_in = (const float*)d_in[2];
  const float* W_ih = (const float*)d_in[3];
  const float* W_hh = (const float*)d_in[4];
  const float* b_ih = (const float*)d_in[5];
  const float* b_hh = (const float*)d_in[6];
  float* out = (float*)d_out;

  const bool use_ws = ws_size >= (size_t)WSZ * 4;
  unsigned int* w16 = (unsigned int*)d_ws;

  if (use_ws) {
    hipLaunchKernelGGL(convert_wih, dim3((WSZ + 255) / 256), dim3(256), 0, stream, W_ih, w16);
    hipLaunchKernelGGL((gru_scan_kernel<true>), dim3(Bn), dim3(512), 0, stream,
                       times_in, data_in, mask_in, w16, W_ih, W_hh, b_ih, b_hh, out);
  } else {
    hipLaunchKernelGGL((gru_scan_kernel<false>), dim3(Bn), dim3(512), 0, stream,
                       times_in, data_in, mask_in, (const unsigned int*)nullptr, W_ih, W_hh,
                       b_ih, b_hh, out);
  }
}

// Round 4
// 797.400 us; speedup vs baseline: 9.0361x; 1.5852x over previous
//
#include <hip/hip_runtime.h>

#define Bn 256
#define Tn 512
#define Vn 64
#define Hn 256
#define INn 129
#define Cc 8                 // timesteps per chunk (fallback path)
#define NCH (Tn / Cc)
#define WU 68                // packed uints per W_ih row (136 f16 cols)
#define WSZ (768 * WU)       // uints for packed W_ih
#define GX_OFF (262144)      // byte offset of gx in ws (256 KB, past w16+pad)
#define GX_BYTES ((size_t)Bn * Tn * 768 * 2)
#define AST 168              // A-tile LDS stride in halves (2-way-only bank aliasing)

typedef __fp16 half2_t __attribute__((ext_vector_type(2)));
typedef __fp16 half8_t __attribute__((ext_vector_type(8)));
typedef float f32x4 __attribute__((ext_vector_type(4)));

static __device__ __forceinline__ unsigned int cvt2(float a, float b) {
  return __builtin_bit_cast(unsigned int, __builtin_amdgcn_cvt_pkrtz(a, b));
}

static __device__ __forceinline__ float dot2(unsigned int w, unsigned int x, float acc) {
#if __has_builtin(__builtin_amdgcn_fdot2)
  return __builtin_amdgcn_fdot2(__builtin_bit_cast(half2_t, w),
                                __builtin_bit_cast(half2_t, x), acc, false);
#else
  half2_t a = __builtin_bit_cast(half2_t, w);
  half2_t b = __builtin_bit_cast(half2_t, x);
  return acc + (float)a.x * (float)b.x + (float)a.y * (float)b.y;
#endif
}

static __device__ __forceinline__ float xor1_add(float v) {
  int i = __builtin_bit_cast(int, v);
  int j = __builtin_amdgcn_ds_swizzle(i, 0x041F);  // xor lane^1
  return v + __builtin_bit_cast(float, j);
}

static __device__ __forceinline__ float fast_exp2(float x) {
#if __has_builtin(__builtin_amdgcn_exp2f)
  return __builtin_amdgcn_exp2f(x);
#else
  return exp2f(x);
#endif
}
static __device__ __forceinline__ float fast_rcp(float x) {
#if __has_builtin(__builtin_amdgcn_rcpf)
  return __builtin_amdgcn_rcpf(x);
#else
  return 1.f / x;
#endif
}
static __device__ __forceinline__ float sigmoid_f(float x) {
  return fast_rcp(1.f + fast_exp2(-1.44269504f * x));
}
static __device__ __forceinline__ float tanh_f(float x) {
  return 1.f - 2.f * fast_rcp(1.f + fast_exp2(2.88539008f * x));
}

// Pack W_ih (768x129 f32) into [768][68] f16-pair uints in workspace (cols >=129 zero).
__global__ void convert_wih(const float* __restrict__ W_ih, unsigned int* __restrict__ w16) {
  int idx = blockIdx.x * 256 + threadIdx.x;
  if (idx >= WSZ) return;
  int j = idx / WU, c = idx - j * WU;
  int col = 2 * c;
  float f0 = (col < INn) ? W_ih[(size_t)j * INn + col] : 0.f;
  float f1 = (col + 1 < INn) ? W_ih[(size_t)j * INn + col + 1] : 0.f;
  w16[idx] = cvt2(f0, f1);
}

// ---------------- GEMM: gx[b][t][n] = x[b][t] . W_ih[n] + b_ih[n]  (f16 out) -------------
// Grid (2048, 3): x = b*8 + tchunk, y = n-block of 256. Block 256 thr = 4 waves.
// Wave w: out tile 64 t-rows x 64 cols (4 m-tiles x 4 n-tiles of 16x16), K = 160 (padded).
__global__ __launch_bounds__(256, 4)
void gx_gemm(const float* __restrict__ times_in, const float* __restrict__ data_in,
             const float* __restrict__ mask_in, const unsigned int* __restrict__ w16,
             const float* __restrict__ b_ih, __fp16* __restrict__ gx) {
  __shared__ __align__(16) __fp16 xa[64 * AST];  // 21504 B

  const int tid = threadIdx.x;
  const int bt = blockIdx.x;
  const int b = bt >> 3, tc = bt & 7;
  const int t0 = tc * 64;
  const int n0 = blockIdx.y * 256;

  // ---- stage A: 64 rows x {data(64)|mask(64)|delta|pad} halves, f32->f16 ----
  {
    int r = tid >> 2, s = tid & 3;  // row 0..63, quarter 0..3
    const float* src = (s < 2)
        ? data_in + ((size_t)b * Tn + t0 + r) * Vn + s * 32
        : mask_in + ((size_t)b * Tn + t0 + r) * Vn + (s - 2) * 32;
    unsigned int* dst = (unsigned int*)(xa + r * AST) + s * 16;
#pragma unroll
    for (int i = 0; i < 8; ++i) {
      float4 v = ((const float4*)src)[i];
      dst[2 * i] = cvt2(v.x, v.y);
      dst[2 * i + 1] = cvt2(v.z, v.w);
    }
  }
  if (tid < 64) {
    int g = t0 + tid;
    float tcur = times_in[(size_t)b * Tn + g];
    float d = (g < Tn - 1) ? times_in[(size_t)b * Tn + g + 1] - tcur : 0.f;
    unsigned int* p = (unsigned int*)(xa + tid * AST + 128);
    p[0] = cvt2(d, 0.f);
#pragma unroll
    for (int i = 1; i < 20; ++i) p[i] = 0u;  // halves 130..167 zero
  }
  __syncthreads();

  const int w = tid >> 6, lane = tid & 63;
  const int m = lane & 15, q = lane >> 4;
  const int nw = n0 + w * 64;

  f32x4 acc[4][4];
#pragma unroll
  for (int i = 0; i < 4; ++i)
#pragma unroll
    for (int j = 0; j < 4; ++j) acc[i][j] = f32x4{0.f, 0.f, 0.f, 0.f};

#pragma unroll
  for (int kt = 0; kt < 5; ++kt) {
    const int k0 = kt * 32 + q * 8;  // halves
    half8_t bf[4], af[4];
#pragma unroll
    for (int nt = 0; nt < 4; ++nt) {
      int n = nw + nt * 16 + m;  // B operand: n = lane&15
      uint4 bv = *(const uint4*)(w16 + (size_t)n * WU + (k0 >> 1));
      bf[nt] = __builtin_bit_cast(half8_t, bv);
    }
#pragma unroll
    for (int mt = 0; mt < 4; ++mt) {
      uint4 av = *(const uint4*)(xa + (mt * 16 + m) * AST + k0);
      af[mt] = __builtin_bit_cast(half8_t, av);
    }
#pragma unroll
    for (int mt = 0; mt < 4; ++mt)
#pragma unroll
      for (int nt = 0; nt < 4; ++nt)
        acc[mt][nt] = __builtin_amdgcn_mfma_f32_16x16x32_f16(af[mt], bf[nt], acc[mt][nt], 0, 0, 0);
  }

  // epilogue: C/D layout col=lane&15, row=q*4+reg
  float bias[4];
#pragma unroll
  for (int nt = 0; nt < 4; ++nt) bias[nt] = b_ih[nw + nt * 16 + m];
#pragma unroll
  for (int mt = 0; mt < 4; ++mt) {
    int trow = t0 + mt * 16 + q * 4;
#pragma unroll
    for (int nt = 0; nt < 4; ++nt) {
      int n = nw + nt * 16 + m;
#pragma unroll
      for (int r = 0; r < 4; ++r) {
        gx[((size_t)b * Tn + trow + r) * 768 + n] = (__fp16)(acc[mt][nt][r] + bias[nt]);
      }
    }
  }
}

// ---------------- Scan: phase B only; gx streamed from global with 2-step prefetch ----------
__global__ __launch_bounds__(512, 2)
void gru_scan2(const float* __restrict__ times_in, const float* __restrict__ W_hh,
               const float* __restrict__ b_hh, const __fp16* __restrict__ gx,
               float* __restrict__ out) {
  __shared__ __align__(16) __fp16 h_buf[2 * Hn];
  __shared__ __align__(16) float t_lds[Tn];

  const int tid = threadIdx.x;
  const int b = blockIdx.x;
  const int jg = tid >> 1;
  const int ks = tid & 1;

  t_lds[tid] = times_in[(size_t)b * Tn + tid];

  unsigned int whr[64], whz[64], whn[64];
  {
    const float* w0 = W_hh + (size_t)jg * Hn + ks * 128;
    const float* w1 = W_hh + (size_t)(jg + 256) * Hn + ks * 128;
    const float* w2 = W_hh + (size_t)(jg + 512) * Hn + ks * 128;
#pragma unroll
    for (int c = 0; c < 64; ++c) {
      whr[c] = cvt2(w0[2 * c], w0[2 * c + 1]);
      whz[c] = cvt2(w1[2 * c], w1[2 * c + 1]);
      whn[c] = cvt2(w2[2 * c], w2[2 * c + 1]);
    }
  }
  const float brh = b_hh[jg];
  const float bzh = b_hh[jg + 256];
  const float bhn = b_hh[jg + 512];

  h_buf[tid] = (__fp16)0.f;
  __syncthreads();

  const __fp16* gxb = gx + (size_t)b * Tn * 768;
  float hcur = 0.f;

  auto step = [&](int t, int curbuf, float gr, float gz, float gn) {
    float sr = 0.f, sz = 0.f, shn = 0.f;
    const uint4* hb = (const uint4*)(h_buf + curbuf * Hn + ks * 128);
#pragma unroll
    for (int c = 0; c < 16; ++c) {
      uint4 hv = hb[c];
      sr = dot2(whr[4 * c + 0], hv.x, sr);
      sz = dot2(whz[4 * c + 0], hv.x, sz);
      shn = dot2(whn[4 * c + 0], hv.x, shn);
      sr = dot2(whr[4 * c + 1], hv.y, sr);
      sz = dot2(whz[4 * c + 1], hv.y, sz);
      shn = dot2(whn[4 * c + 1], hv.y, shn);
      sr = dot2(whr[4 * c + 2], hv.z, sr);
      sz = dot2(whz[4 * c + 2], hv.z, sz);
      shn = dot2(whn[4 * c + 2], hv.z, shn);
      sr = dot2(whr[4 * c + 3], hv.w, sr);
      sz = dot2(whz[4 * c + 3], hv.w, sz);
      shn = dot2(whn[4 * c + 3], hv.w, shn);
    }
    sr = xor1_add(sr);
    sz = xor1_add(sz);
    shn = xor1_add(shn);
    float r = sigmoid_f(gr + sr + brh);
    float z = sigmoid_f(gz + sz + bzh);
    float n = tanh_f(gn + r * (shn + bhn));
    float hN = (1.f - z) * n + z * hcur;
    hcur = (t_lds[t] > 0.f) ? hN : hcur;
    if (ks == 0) h_buf[(curbuf ^ 1) * Hn + jg] = (__fp16)hcur;
    __syncthreads();
  };

  float g0r = (float)gxb[jg], g0z = (float)gxb[256 + jg], g0n = (float)gxb[512 + jg];
  float g1r = (float)gxb[768 + jg], g1z = (float)gxb[768 + 256 + jg],
        g1n = (float)gxb[768 + 512 + jg];

#pragma unroll 1
  for (int t = 0; t < Tn; t += 2) {
    __fp16 ar = (__fp16)0.f, az = (__fp16)0.f, an = (__fp16)0.f;
    __fp16 cr = (__fp16)0.f, cz = (__fp16)0.f, cn = (__fp16)0.f;
    if (t + 2 < Tn) {
      const __fp16* p = gxb + (size_t)(t + 2) * 768;
      ar = p[jg]; az = p[256 + jg]; an = p[512 + jg];
    }
    if (t + 3 < Tn) {
      const __fp16* p = gxb + (size_t)(t + 3) * 768;
      cr = p[jg]; cz = p[256 + jg]; cn = p[512 + jg];
    }
    step(t, 0, g0r, g0z, g0n);
    step(t + 1, 1, g1r, g1z, g1n);
    g0r = (float)ar; g0z = (float)az; g0n = (float)an;
    g1r = (float)cr; g1z = (float)cz; g1n = (float)cn;
  }

  if (ks == 0) out[(size_t)b * Hn + jg] = hcur;
}

// ---------------- Fallback (R3): in-kernel phase A, used only if ws too small -------------
template <bool USE_WS>
static __device__ __forceinline__ void phaseA_pass(int col, const unsigned int* __restrict__ w16,
                                                   const float* __restrict__ W_ih,
                                                   const unsigned int* x_lds, float* a) {
  const uint4* wp = (const uint4*)(w16) + (size_t)col * (WU / 4);
  const float* wf = W_ih + (size_t)col * INn;
#pragma unroll 2
  for (int kp = 0; kp < 8; ++kp) {
    uint4 wa, wb;
    if constexpr (USE_WS) {
      wa = wp[2 * kp];
      wb = wp[2 * kp + 1];
    } else {
      const float* f = wf + 16 * kp;
      wa.x = cvt2(f[0], f[1]);   wa.y = cvt2(f[2], f[3]);
      wa.z = cvt2(f[4], f[5]);   wa.w = cvt2(f[6], f[7]);
      wb.x = cvt2(f[8], f[9]);   wb.y = cvt2(f[10], f[11]);
      wb.z = cvt2(f[12], f[13]); wb.w = cvt2(f[14], f[15]);
    }
#pragma unroll
    for (int t = 0; t < Cc; ++t) {
      const uint4* xp = (const uint4*)&x_lds[t * WU + kp * 8];
      uint4 xa = xp[0], xb = xp[1];
      a[t] = dot2(wa.x, xa.x, a[t]);
      a[t] = dot2(wa.y, xa.y, a[t]);
      a[t] = dot2(wa.z, xa.z, a[t]);
      a[t] = dot2(wa.w, xa.w, a[t]);
      a[t] = dot2(wb.x, xb.x, a[t]);
      a[t] = dot2(wb.y, xb.y, a[t]);
      a[t] = dot2(wb.z, xb.z, a[t]);
      a[t] = dot2(wb.w, xb.w, a[t]);
    }
  }
  uint4 wt;
  if constexpr (USE_WS) {
    wt = wp[16];
  } else {
    wt.x = cvt2(wf[128], 0.f); wt.y = 0u; wt.z = 0u; wt.w = 0u;
  }
#pragma unroll
  for (int t = 0; t < Cc; ++t) {
    uint4 xt = *(const uint4*)&x_lds[t * WU + 64];
    a[t] = dot2(wt.x, xt.x, a[t]);
    a[t] = dot2(wt.y, xt.y, a[t]);
  }
}

template <bool USE_WS>
__global__ __launch_bounds__(512, 2)
void gru_scan_fb(const float* __restrict__ times_in, const float* __restrict__ data_in,
                 const float* __restrict__ mask_in, const unsigned int* __restrict__ w16,
                 const float* __restrict__ W_ih, const float* __restrict__ W_hh,
                 const float* __restrict__ b_ih, const float* __restrict__ b_hh,
                 float* __restrict__ out) {
  __shared__ __align__(16) float gx_lds[Cc * 768];
  __shared__ __align__(16) unsigned int x_lds[Cc * WU];
  __shared__ __align__(16) __fp16 h_buf[2 * Hn];
  __shared__ __align__(16) float t_lds[Tn];

  const int tid = threadIdx.x;
  const int b = blockIdx.x;
  const int jg = tid >> 1;
  const int ks = tid & 1;

  t_lds[tid] = times_in[(size_t)b * Tn + tid];

  unsigned int whr[64], whz[64], whn[64];
  {
    const float* w0 = W_hh + (size_t)jg * Hn + ks * 128;
    const float* w1 = W_hh + (size_t)(jg + 256) * Hn + ks * 128;
    const float* w2 = W_hh + (size_t)(jg + 512) * Hn + ks * 128;
#pragma unroll
    for (int c = 0; c < 64; ++c) {
      whr[c] = cvt2(w0[2 * c], w0[2 * c + 1]);
      whz[c] = cvt2(w1[2 * c], w1[2 * c + 1]);
      whn[c] = cvt2(w2[2 * c], w2[2 * c + 1]);
    }
  }
  const float brh = b_hh[jg];
  const float bzh = b_hh[jg + 256];
  const float bhn = b_hh[jg + 512];
  const float bi1 = b_ih[tid];
  const float bi2 = (tid < 256) ? b_ih[512 + tid] : 0.f;

  h_buf[tid] = (__fp16)0.f;
  __syncthreads();

  float hcur = 0.f;
  int cur = 0;
#pragma unroll 1
  for (int ch = 0; ch < NCH; ++ch) {
    const int t0 = ch * Cc;
    {
      int t = tid >> 6;
      int c = tid & 63;
      const float* src = (c < 32)
          ? data_in + ((size_t)b * Tn + t0 + t) * Vn + 2 * c
          : mask_in + ((size_t)b * Tn + t0 + t) * Vn + 2 * (c - 32);
      float2 v = *(const float2*)src;
      x_lds[t * WU + c] = cvt2(v.x, v.y);
      if (tid < Cc) {
        int g = t0 + tid;
        float d = (g < Tn - 1) ? (t_lds[g + 1] - t_lds[g]) : 0.f;
        uint4 tl;
        tl.x = cvt2(d, 0.f); tl.y = 0u; tl.z = 0u; tl.w = 0u;
        *(uint4*)&x_lds[tid * WU + 64] = tl;
      }
    }
    __syncthreads();
    {
      float a[Cc];
#pragma unroll
      for (int t = 0; t < Cc; ++t) a[t] = bi1;
      phaseA_pass<USE_WS>(tid, w16, W_ih, x_lds, a);
#pragma unroll
      for (int t = 0; t < Cc; ++t) gx_lds[t * 768 + tid] = a[t];
      if (tid < 256) {
#pragma unroll
        for (int t = 0; t < Cc; ++t) a[t] = bi2;
        phaseA_pass<USE_WS>(512 + tid, w16, W_ih, x_lds, a);
#pragma unroll
        for (int t = 0; t < Cc; ++t) gx_lds[t * 768 + 512 + tid] = a[t];
      }
    }
    __syncthreads();
    for (int tt = 0; tt < Cc; ++tt) {
      float sr = 0.f, sz = 0.f, shn = 0.f;
      const uint4* hb = (const uint4*)(h_buf + cur * Hn + ks * 128);
#pragma unroll
      for (int c = 0; c < 16; ++c) {
        uint4 hv = hb[c];
        sr = dot2(whr[4 * c + 0], hv.x, sr);
        sz = dot2(whz[4 * c + 0], hv.x, sz);
        shn = dot2(whn[4 * c + 0], hv.x, shn);
        sr = dot2(whr[4 * c + 1], hv.y, sr);
        sz = dot2(whz[4 * c + 1], hv.y, sz);
        shn = dot2(whn[4 * c + 1], hv.y, shn);
        sr = dot2(whr[4 * c + 2], hv.z, sr);
        sz = dot2(whz[4 * c + 2], hv.z, sz);
        shn = dot2(whn[4 * c + 2], hv.z, shn);
        sr = dot2(whr[4 * c + 3], hv.w, sr);
        sz = dot2(whz[4 * c + 3], hv.w, sz);
        shn = dot2(whn[4 * c + 3], hv.w, shn);
      }
      float gxr = gx_lds[tt * 768 + jg];
      float gxz = gx_lds[tt * 768 + 256 + jg];
      float gxn = gx_lds[tt * 768 + 512 + jg];
      sr = xor1_add(sr);
      sz = xor1_add(sz);
      shn = xor1_add(shn);
      float r = sigmoid_f(gxr + sr + brh);
      float z = sigmoid_f(gxz + sz + bzh);
      float n = tanh_f(gxn + r * (shn + bhn));
      float hN = (1.f - z) * n + z * hcur;
      hcur = (t_lds[t0 + tt] > 0.f) ? hN : hcur;
      if (ks == 0) h_buf[(cur ^ 1) * Hn + jg] = (__fp16)hcur;
      __syncthreads();
      cur ^= 1;
    }
  }
  if (ks == 0) out[(size_t)b * Hn + jg] = hcur;
}

extern "C" void kernel_launch(void* const* d_in, const int* in_sizes, int n_in,
                              void* d_out, int out_size, void* d_ws, size_t ws_size,
                              hipStream_t stream) {
  const float* times_in = (const float*)d_in[0];
  const float* data_in = (const float*)d_in[1];
  const float* mask_in = (const float*)d_in[2];
  const float* W_ih = (const float*)d_in[3];
  const float* W_hh = (const float*)d_in[4];
  const float* b_ih = (const float*)d_in[5];
  const float* b_hh = (const float*)d_in[6];
  float* out = (float*)d_out;

  unsigned int* w16 = (unsigned int*)d_ws;
  __fp16* gx = (__fp16*)((char*)d_ws + GX_OFF);

  if (ws_size >= GX_OFF + GX_BYTES) {
    hipLaunchKernelGGL(convert_wih, dim3((WSZ + 255) / 256), dim3(256), 0, stream, W_ih, w16);
    hipLaunchKernelGGL(gx_gemm, dim3(2048, 3), dim3(256), 0, stream,
                       times_in, data_in, mask_in, w16, b_ih, gx);
    hipLaunchKernelGGL(gru_scan2, dim3(Bn), dim3(512), 0, stream,
                       times_in, W_hh, b_hh, gx, out);
  } else if (ws_size >= (size_t)WSZ * 4) {
    hipLaunchKernelGGL(convert_wih, dim3((WSZ + 255) / 256), dim3(256), 0, stream, W_ih, w16);
    hipLaunchKernelGGL((gru_scan_fb<true>), dim3(Bn), dim3(512), 0, stream,
                       times_in, data_in, mask_in, w16, W_ih, W_hh, b_ih, b_hh, out);
  } else {
    hipLaunchKernelGGL((gru_scan_fb<false>), dim3(Bn), dim3(512), 0, stream,
                       times_in, data_in, mask_in, (const unsigned int*)nullptr, W_ih, W_hh,
                       b_ih, b_hh, out);
  }
}

// Round 5
// 781.462 us; speedup vs baseline: 9.2203x; 1.0204x over previous
//
#include <hip/hip_runtime.h>

#define Bn 256
#define Tn 512
#define Vn 64
#define Hn 256
#define INn 129
#define Cc 8                 // timesteps per chunk (fallback path)
#define NCH (Tn / Cc)
#define WU 68                // packed uints per W_ih row (136 f16 cols)
#define WSZ (768 * WU)       // uints for packed W_ih
#define GX_OFF (262144)      // byte offset of gx in ws
#define GX_BYTES ((size_t)Bn * Tn * 768 * 2)
#define AST 168              // A-tile LDS stride in halves (staging)
#define CST 264              // C-tile LDS stride in halves (epilogue transpose)

typedef __fp16 half2_t __attribute__((ext_vector_type(2)));
typedef __fp16 half8_t __attribute__((ext_vector_type(8)));
typedef float f32x4 __attribute__((ext_vector_type(4)));

static __device__ __forceinline__ unsigned int cvt2(float a, float b) {
  return __builtin_bit_cast(unsigned int, __builtin_amdgcn_cvt_pkrtz(a, b));
}

static __device__ __forceinline__ float dot2(unsigned int w, unsigned int x, float acc) {
#if __has_builtin(__builtin_amdgcn_fdot2)
  return __builtin_amdgcn_fdot2(__builtin_bit_cast(half2_t, w),
                                __builtin_bit_cast(half2_t, x), acc, false);
#else
  half2_t a = __builtin_bit_cast(half2_t, w);
  half2_t b = __builtin_bit_cast(half2_t, x);
  return acc + (float)a.x * (float)b.x + (float)a.y * (float)b.y;
#endif
}

// pair-sum across lanes 2i<->2i+1 on the VALU pipe (DPP quad_perm [1,0,3,2])
static __device__ __forceinline__ float pair_sum(float v) {
#if __has_builtin(__builtin_amdgcn_update_dpp)
  int x = __builtin_amdgcn_update_dpp(0, __builtin_bit_cast(int, v), 0xB1, 0xF, 0xF, true);
  return v + __builtin_bit_cast(float, x);
#else
  int j = __builtin_amdgcn_ds_swizzle(__builtin_bit_cast(int, v), 0x041F);
  return v + __builtin_bit_cast(float, j);
#endif
}

static __device__ __forceinline__ float fast_exp2(float x) {
#if __has_builtin(__builtin_amdgcn_exp2f)
  return __builtin_amdgcn_exp2f(x);
#else
  return exp2f(x);
#endif
}
static __device__ __forceinline__ float fast_rcp(float x) {
#if __has_builtin(__builtin_amdgcn_rcpf)
  return __builtin_amdgcn_rcpf(x);
#else
  return 1.f / x;
#endif
}
static __device__ __forceinline__ float sigmoid_f(float x) {
  return fast_rcp(1.f + fast_exp2(-1.44269504f * x));
}
static __device__ __forceinline__ float tanh_f(float x) {
  return 1.f - 2.f * fast_rcp(1.f + fast_exp2(2.88539008f * x));
}

// Pack W_ih (768x129 f32) into [768][68] f16-pair uints in workspace (cols >=129 zero).
__global__ void convert_wih(const float* __restrict__ W_ih, unsigned int* __restrict__ w16) {
  int idx = blockIdx.x * 256 + threadIdx.x;
  if (idx >= WSZ) return;
  int j = idx / WU, c = idx - j * WU;
  int col = 2 * c;
  float f0 = (col < INn) ? W_ih[(size_t)j * INn + col] : 0.f;
  float f1 = (col + 1 < INn) ? W_ih[(size_t)j * INn + col + 1] : 0.f;
  w16[idx] = cvt2(f0, f1);
}

// ---------------- GEMM: gx[b][t][n] = x[b][t] . W_ih[n] + b_ih[n]  (f16 out) -------------
__global__ __launch_bounds__(256, 4)
void gx_gemm(const float* __restrict__ times_in, const float* __restrict__ data_in,
             const float* __restrict__ mask_in, const unsigned int* __restrict__ w16,
             const float* __restrict__ b_ih, __fp16* __restrict__ gx) {
  __shared__ __align__(16) char raw[64 * CST * 2];  // 33792 B: staging (stride AST) then C-tile (stride CST)
  __fp16* xa = (__fp16*)raw;
  __fp16* ct = (__fp16*)raw;

  const int tid = threadIdx.x;
  const int bt = blockIdx.x;
  const int b = bt >> 3, tc = bt & 7;
  const int t0 = tc * 64;
  const int n0 = blockIdx.y * 256;

  // ---- stage A: 64 rows x {data(64)|mask(64)|delta|pad} halves, f32->f16 ----
  {
    int r = tid >> 2, s = tid & 3;
    const float* src = (s < 2)
        ? data_in + ((size_t)b * Tn + t0 + r) * Vn + s * 32
        : mask_in + ((size_t)b * Tn + t0 + r) * Vn + (s - 2) * 32;
    unsigned int* dst = (unsigned int*)(xa + r * AST) + s * 16;
#pragma unroll
    for (int i = 0; i < 8; ++i) {
      float4 v = ((const float4*)src)[i];
      dst[2 * i] = cvt2(v.x, v.y);
      dst[2 * i + 1] = cvt2(v.z, v.w);
    }
  }
  if (tid < 64) {
    int g = t0 + tid;
    float tcur = times_in[(size_t)b * Tn + g];
    float d = (g < Tn - 1) ? times_in[(size_t)b * Tn + g + 1] - tcur : 0.f;
    unsigned int* p = (unsigned int*)(xa + tid * AST + 128);
    p[0] = cvt2(d, 0.f);
#pragma unroll
    for (int i = 1; i < 20; ++i) p[i] = 0u;
  }
  __syncthreads();

  const int w = tid >> 6, lane = tid & 63;
  const int m = lane & 15, q = lane >> 4;
  const int nw = n0 + w * 64;

  f32x4 acc[4][4];
#pragma unroll
  for (int i = 0; i < 4; ++i)
#pragma unroll
    for (int j = 0; j < 4; ++j) acc[i][j] = f32x4{0.f, 0.f, 0.f, 0.f};

#pragma unroll
  for (int kt = 0; kt < 5; ++kt) {
    const int k0 = kt * 32 + q * 8;
    half8_t bf[4], af[4];
#pragma unroll
    for (int nt = 0; nt < 4; ++nt) {
      int n = nw + nt * 16 + m;
      uint4 bv = *(const uint4*)(w16 + (size_t)n * WU + (k0 >> 1));
      bf[nt] = __builtin_bit_cast(half8_t, bv);
    }
#pragma unroll
    for (int mt = 0; mt < 4; ++mt) {
      uint4 av = *(const uint4*)(xa + (mt * 16 + m) * AST + k0);
      af[mt] = __builtin_bit_cast(half8_t, av);
    }
#pragma unroll
    for (int mt = 0; mt < 4; ++mt)
#pragma unroll
      for (int nt = 0; nt < 4; ++nt)
        acc[mt][nt] = __builtin_amdgcn_mfma_f32_16x16x32_f16(af[mt], bf[nt], acc[mt][nt], 0, 0, 0);
  }

  float bias[4];
#pragma unroll
  for (int nt = 0; nt < 4; ++nt) bias[nt] = b_ih[nw + nt * 16 + m];

  __syncthreads();  // staging reads done; reuse LDS as C-tile
  // C/D layout: col(n)=lane&15, row(t)=q*4+reg. Write to ct[t][n-n0], stride CST.
#pragma unroll
  for (int mt = 0; mt < 4; ++mt)
#pragma unroll
    for (int nt = 0; nt < 4; ++nt)
#pragma unroll
      for (int r = 0; r < 4; ++r)
        ct[(mt * 16 + q * 4 + r) * CST + w * 64 + nt * 16 + m] =
            (__fp16)(acc[mt][nt][r] + bias[nt]);
  __syncthreads();

  // coalesced store: thread -> row tt = tid>>2, quarter qq = tid&3 (8 uint4 each)
  {
    const int tt = tid >> 2, qq = tid & 3;
    const uint4* src = (const uint4*)(ct + tt * CST) + qq * 8;
    uint4* dst = (uint4*)(gx + ((size_t)b * Tn + t0 + tt) * 768 + n0) + qq * 8;
#pragma unroll
    for (int i = 0; i < 8; ++i) dst[i] = src[i];
  }
}

// ---------------- Scan: phase B only; chunked h reads, DPP reduction ----------------------
__global__ __launch_bounds__(512, 2)
void gru_scan2(const float* __restrict__ times_in, const float* __restrict__ W_hh,
               const float* __restrict__ b_hh, const __fp16* __restrict__ gx,
               float* __restrict__ out) {
  __shared__ __align__(16) __fp16 h_buf[2 * Hn];
  __shared__ __align__(16) float t_lds[Tn];

  const int tid = threadIdx.x;
  const int b = blockIdx.x;
  const int jg = tid >> 1;
  const int ks = tid & 1;

  t_lds[tid] = times_in[(size_t)b * Tn + tid];

  unsigned int whr[64], whz[64], whn[64];
  {
    const float* w0 = W_hh + (size_t)jg * Hn + ks * 128;
    const float* w1 = W_hh + (size_t)(jg + 256) * Hn + ks * 128;
    const float* w2 = W_hh + (size_t)(jg + 512) * Hn + ks * 128;
#pragma unroll
    for (int c = 0; c < 64; ++c) {
      whr[c] = cvt2(w0[2 * c], w0[2 * c + 1]);
      whz[c] = cvt2(w1[2 * c], w1[2 * c + 1]);
      whn[c] = cvt2(w2[2 * c], w2[2 * c + 1]);
    }
  }
  const float brh = b_hh[jg];
  const float bzh = b_hh[jg + 256];
  const float bhn = b_hh[jg + 512];

  h_buf[tid] = (__fp16)0.f;
  __syncthreads();

  const __fp16* gxb = gx + (size_t)b * Tn * 768;
  float hcur = 0.f;

  // preload step-0 gx + mask-time
  float gr = (float)gxb[jg], gz = (float)gxb[256 + jg], gn = (float)gxb[512 + jg];
  float mt = t_lds[0];

#pragma unroll 1
  for (int t = 0; t < Tn; ++t) {
    // prefetch step t+1 (global f16 + LDS time); latency hidden under this step's dots
    __fp16 pr = (__fp16)0.f, pz = (__fp16)0.f, pn = (__fp16)0.f;
    float mtn = 0.f;
    if (t + 1 < Tn) {
      const __fp16* p = gxb + (size_t)(t + 1) * 768;
      pr = p[jg]; pz = p[256 + jg]; pn = p[512 + jg];
      mtn = t_lds[t + 1];
    }

    const int cur = t & 1;
    const uint4* hb = (const uint4*)(h_buf + cur * Hn) + ks * 16;

    float sr = 0.f, sz = 0.f, shn = 0.f;
    // chunked h-broadcast: 2 uint4 in flight, rotating prefetch (keeps VGPR peak < 256)
    uint4 p0 = hb[0], p1 = hb[1];
#pragma unroll
    for (int cc = 0; cc < 8; ++cc) {
      uint4 q0 = p0, q1 = p1;
      if (cc < 7) { q0 = hb[2 * cc + 2]; q1 = hb[2 * cc + 3]; }
      const int cb = cc * 8;
      sr = dot2(whr[cb + 0], p0.x, sr);
      sz = dot2(whz[cb + 0], p0.x, sz);
      shn = dot2(whn[cb + 0], p0.x, shn);
      sr = dot2(whr[cb + 1], p0.y, sr);
      sz = dot2(whz[cb + 1], p0.y, sz);
      shn = dot2(whn[cb + 1], p0.y, shn);
      sr = dot2(whr[cb + 2], p0.z, sr);
      sz = dot2(whz[cb + 2], p0.z, sz);
      shn = dot2(whn[cb + 2], p0.z, shn);
      sr = dot2(whr[cb + 3], p0.w, sr);
      sz = dot2(whz[cb + 3], p0.w, sz);
      shn = dot2(whn[cb + 3], p0.w, shn);
      sr = dot2(whr[cb + 4], p1.x, sr);
      sz = dot2(whz[cb + 4], p1.x, sz);
      shn = dot2(whn[cb + 4], p1.x, shn);
      sr = dot2(whr[cb + 5], p1.y, sr);
      sz = dot2(whz[cb + 5], p1.y, sz);
      shn = dot2(whn[cb + 5], p1.y, shn);
      sr = dot2(whr[cb + 6], p1.z, sr);
      sz = dot2(whz[cb + 6], p1.z, sz);
      shn = dot2(whn[cb + 6], p1.z, shn);
      sr = dot2(whr[cb + 7], p1.w, sr);
      sz = dot2(whz[cb + 7], p1.w, sz);
      shn = dot2(whn[cb + 7], p1.w, shn);
      p0 = q0; p1 = q1;
    }

    // reduce the two k-halves on the VALU pipe (no LDS)
    sr = pair_sum(sr);
    sz = pair_sum(sz);
    shn = pair_sum(shn);

    float r = sigmoid_f(gr + sr + brh);
    float z = sigmoid_f(gz + sz + bzh);
    float n = tanh_f(gn + r * (shn + bhn));
    float hN = (1.f - z) * n + z * hcur;
    hcur = (mt > 0.f) ? hN : hcur;

    if (ks == 0) h_buf[(cur ^ 1) * Hn + jg] = (__fp16)hcur;
    __syncthreads();

    gr = (float)pr; gz = (float)pz; gn = (float)pn; mt = mtn;
  }

  if (ks == 0) out[(size_t)b * Hn + jg] = hcur;
}

// ---------------- Fallback (R3): in-kernel phase A, used only if ws too small -------------
template <bool USE_WS>
static __device__ __forceinline__ void phaseA_pass(int col, const unsigned int* __restrict__ w16,
                                                   const float* __restrict__ W_ih,
                                                   const unsigned int* x_lds, float* a) {
  const uint4* wp = (const uint4*)(w16) + (size_t)col * (WU / 4);
  const float* wf = W_ih + (size_t)col * INn;
#pragma unroll 2
  for (int kp = 0; kp < 8; ++kp) {
    uint4 wa, wb;
    if constexpr (USE_WS) {
      wa = wp[2 * kp];
      wb = wp[2 * kp + 1];
    } else {
      const float* f = wf + 16 * kp;
      wa.x = cvt2(f[0], f[1]);   wa.y = cvt2(f[2], f[3]);
      wa.z = cvt2(f[4], f[5]);   wa.w = cvt2(f[6], f[7]);
      wb.x = cvt2(f[8], f[9]);   wb.y = cvt2(f[10], f[11]);
      wb.z = cvt2(f[12], f[13]); wb.w = cvt2(f[14], f[15]);
    }
#pragma unroll
    for (int t = 0; t < Cc; ++t) {
      const uint4* xp = (const uint4*)&x_lds[t * WU + kp * 8];
      uint4 xa = xp[0], xb = xp[1];
      a[t] = dot2(wa.x, xa.x, a[t]);
      a[t] = dot2(wa.y, xa.y, a[t]);
      a[t] = dot2(wa.z, xa.z, a[t]);
      a[t] = dot2(wa.w, xa.w, a[t]);
      a[t] = dot2(wb.x, xb.x, a[t]);
      a[t] = dot2(wb.y, xb.y, a[t]);
      a[t] = dot2(wb.z, xb.z, a[t]);
      a[t] = dot2(wb.w, xb.w, a[t]);
    }
  }
  uint4 wt;
  if constexpr (USE_WS) {
    wt = wp[16];
  } else {
    wt.x = cvt2(wf[128], 0.f); wt.y = 0u; wt.z = 0u; wt.w = 0u;
  }
#pragma unroll
  for (int t = 0; t < Cc; ++t) {
    uint4 xt = *(const uint4*)&x_lds[t * WU + 64];
    a[t] = dot2(wt.x, xt.x, a[t]);
    a[t] = dot2(wt.y, xt.y, a[t]);
  }
}

template <bool USE_WS>
__global__ __launch_bounds__(512, 2)
void gru_scan_fb(const float* __restrict__ times_in, const float* __restrict__ data_in,
                 const float* __restrict__ mask_in, const unsigned int* __restrict__ w16,
                 const float* __restrict__ W_ih, const float* __restrict__ W_hh,
                 const float* __restrict__ b_ih, const float* __restrict__ b_hh,
                 float* __restrict__ out) {
  __shared__ __align__(16) float gx_lds[Cc * 768];
  __shared__ __align__(16) unsigned int x_lds[Cc * WU];
  __shared__ __align__(16) __fp16 h_buf[2 * Hn];
  __shared__ __align__(16) float t_lds[Tn];

  const int tid = threadIdx.x;
  const int b = blockIdx.x;
  const int jg = tid >> 1;
  const int ks = tid & 1;

  t_lds[tid] = times_in[(size_t)b * Tn + tid];

  unsigned int whr[64], whz[64], whn[64];
  {
    const float* w0 = W_hh + (size_t)jg * Hn + ks * 128;
    const float* w1 = W_hh + (size_t)(jg + 256) * Hn + ks * 128;
    const float* w2 = W_hh + (size_t)(jg + 512) * Hn + ks * 128;
#pragma unroll
    for (int c = 0; c < 64; ++c) {
      whr[c] = cvt2(w0[2 * c], w0[2 * c + 1]);
      whz[c] = cvt2(w1[2 * c], w1[2 * c + 1]);
      whn[c] = cvt2(w2[2 * c], w2[2 * c + 1]);
    }
  }
  const float brh = b_hh[jg];
  const float bzh = b_hh[jg + 256];
  const float bhn = b_hh[jg + 512];
  const float bi1 = b_ih[tid];
  const float bi2 = (tid < 256) ? b_ih[512 + tid] : 0.f;

  h_buf[tid] = (__fp16)0.f;
  __syncthreads();

  float hcur = 0.f;
  int cur = 0;
#pragma unroll 1
  for (int ch = 0; ch < NCH; ++ch) {
    const int t0 = ch * Cc;
    {
      int t = tid >> 6;
      int c = tid & 63;
      const float* src = (c < 32)
          ? data_in + ((size_t)b * Tn + t0 + t) * Vn + 2 * c
          : mask_in + ((size_t)b * Tn + t0 + t) * Vn + 2 * (c - 32);
      float2 v = *(const float2*)src;
      x_lds[t * WU + c] = cvt2(v.x, v.y);
      if (tid < Cc) {
        int g = t0 + tid;
        float d = (g < Tn - 1) ? (t_lds[g + 1] - t_lds[g]) : 0.f;
        uint4 tl;
        tl.x = cvt2(d, 0.f); tl.y = 0u; tl.z = 0u; tl.w = 0u;
        *(uint4*)&x_lds[tid * WU + 64] = tl;
      }
    }
    __syncthreads();
    {
      float a[Cc];
#pragma unroll
      for (int t = 0; t < Cc; ++t) a[t] = bi1;
      phaseA_pass<USE_WS>(tid, w16, W_ih, x_lds, a);
#pragma unroll
      for (int t = 0; t < Cc; ++t) gx_lds[t * 768 + tid] = a[t];
      if (tid < 256) {
#pragma unroll
        for (int t = 0; t < Cc; ++t) a[t] = bi2;
        phaseA_pass<USE_WS>(512 + tid, w16, W_ih, x_lds, a);
#pragma unroll
        for (int t = 0; t < Cc; ++t) gx_lds[t * 768 + 512 + tid] = a[t];
      }
    }
    __syncthreads();
    for (int tt = 0; tt < Cc; ++tt) {
      float sr = 0.f, sz = 0.f, shn = 0.f;
      const uint4* hb = (const uint4*)(h_buf + cur * Hn + ks * 128);
#pragma unroll
      for (int c = 0; c < 16; ++c) {
        uint4 hv = hb[c];
        sr = dot2(whr[4 * c + 0], hv.x, sr);
        sz = dot2(whz[4 * c + 0], hv.x, sz);
        shn = dot2(whn[4 * c + 0], hv.x, shn);
        sr = dot2(whr[4 * c + 1], hv.y, sr);
        sz = dot2(whz[4 * c + 1], hv.y, sz);
        shn = dot2(whn[4 * c + 1], hv.y, shn);
        sr = dot2(whr[4 * c + 2], hv.z, sr);
        sz = dot2(whz[4 * c + 2], hv.z, sz);
        shn = dot2(whn[4 * c + 2], hv.z, shn);
        sr = dot2(whr[4 * c + 3], hv.w, sr);
        sz = dot2(whz[4 * c + 3], hv.w, sz);
        shn = dot2(whn[4 * c + 3], hv.w, shn);
      }
      float gxr = gx_lds[tt * 768 + jg];
      float gxz = gx_lds[tt * 768 + 256 + jg];
      float gxn = gx_lds[tt * 768 + 512 + jg];
      sr = pair_sum(sr);
      sz = pair_sum(sz);
      shn = pair_sum(shn);
      float r = sigmoid_f(gxr + sr + brh);
      float z = sigmoid_f(gxz + sz + bzh);
      float n = tanh_f(gxn + r * (shn + bhn));
      float hN = (1.f - z) * n + z * hcur;
      hcur = (t_lds[t0 + tt] > 0.f) ? hN : hcur;
      if (ks == 0) h_buf[(cur ^ 1) * Hn + jg] = (__fp16)hcur;
      __syncthreads();
      cur ^= 1;
    }
  }
  if (ks == 0) out[(size_t)b * Hn + jg] = hcur;
}

extern "C" void kernel_launch(void* const* d_in, const int* in_sizes, int n_in,
                              void* d_out, int out_size, void* d_ws, size_t ws_size,
                              hipStream_t stream) {
  const float* times_in = (const float*)d_in[0];
  const float* data_in = (const float*)d_in[1];
  const float* mask_in = (const float*)d_in[2];
  const float* W_ih = (const float*)d_in[3];
  const float* W_hh = (const float*)d_in[4];
  const float* b_ih = (const float*)d_in[5];
  const float* b_hh = (const float*)d_in[6];
  float* out = (float*)d_out;

  unsigned int* w16 = (unsigned int*)d_ws;
  __fp16* gx = (__fp16*)((char*)d_ws + GX_OFF);

  if (ws_size >= GX_OFF + GX_BYTES) {
    hipLaunchKernelGGL(convert_wih, dim3((WSZ + 255) / 256), dim3(256), 0, stream, W_ih, w16);
    hipLaunchKernelGGL(gx_gemm, dim3(2048, 3), dim3(256), 0, stream,
                       times_in, data_in, mask_in, w16, b_ih, gx);
    hipLaunchKernelGGL(gru_scan2, dim3(Bn), dim3(512), 0, stream,
                       times_in, W_hh, b_hh, gx, out);
  } else if (ws_size >= (size_t)WSZ * 4) {
    hipLaunchKernelGGL(convert_wih, dim3((WSZ + 255) / 256), dim3(256), 0, stream, W_ih, w16);
    hipLaunchKernelGGL((gru_scan_fb<true>), dim3(Bn), dim3(512), 0, stream,
                       times_in, data_in, mask_in, w16, W_ih, W_hh, b_ih, b_hh, out);
  } else {
    hipLaunchKernelGGL((gru_scan_fb<false>), dim3(Bn), dim3(512), 0, stream,
                       times_in, data_in, mask_in, (const unsigned int*)nullptr, W_ih, W_hh,
                       b_ih, b_hh, out);
  }
}

// Round 6
// 777.981 us; speedup vs baseline: 9.2616x; 1.0045x over previous
//
#include <hip/hip_runtime.h>

#define Bn 256
#define Tn 512
#define Vn 64
#define Hn 256
#define INn 129
#define Cc 8                 // timesteps per chunk (fallback path)
#define NCH (Tn / Cc)
#define WU 68                // packed uints per W_ih row (136 f16 cols)
#define WSZ (768 * WU)       // uints for packed W_ih
#define GX_OFF (262144)      // byte offset of gx in ws
#define GX_BYTES ((size_t)Bn * Tn * 768 * 2)
#define AST 168              // A-tile LDS stride in halves (staging)
#define CST 264              // C-tile LDS stride in halves (epilogue transpose)

typedef __fp16 half2_t __attribute__((ext_vector_type(2)));
typedef __fp16 half8_t __attribute__((ext_vector_type(8)));
typedef float f32x4 __attribute__((ext_vector_type(4)));

static __device__ __forceinline__ unsigned int cvt2(float a, float b) {
  return __builtin_bit_cast(unsigned int, __builtin_amdgcn_cvt_pkrtz(a, b));
}

static __device__ __forceinline__ float dot2(unsigned int w, unsigned int x, float acc) {
#if __has_builtin(__builtin_amdgcn_fdot2)
  return __builtin_amdgcn_fdot2(__builtin_bit_cast(half2_t, w),
                                __builtin_bit_cast(half2_t, x), acc, false);
#else
  half2_t a = __builtin_bit_cast(half2_t, w);
  half2_t b = __builtin_bit_cast(half2_t, x);
  return acc + (float)a.x * (float)b.x + (float)a.y * (float)b.y;
#endif
}

// pair-sum across lanes 2i<->2i+1 on the VALU pipe (DPP quad_perm [1,0,3,2])
static __device__ __forceinline__ float pair_sum(float v) {
#if __has_builtin(__builtin_amdgcn_update_dpp)
  int x = __builtin_amdgcn_update_dpp(0, __builtin_bit_cast(int, v), 0xB1, 0xF, 0xF, true);
  return v + __builtin_bit_cast(float, x);
#else
  int j = __builtin_amdgcn_ds_swizzle(__builtin_bit_cast(int, v), 0x041F);
  return v + __builtin_bit_cast(float, j);
#endif
}

static __device__ __forceinline__ float fast_exp2(float x) {
#if __has_builtin(__builtin_amdgcn_exp2f)
  return __builtin_amdgcn_exp2f(x);
#else
  return exp2f(x);
#endif
}
static __device__ __forceinline__ float fast_rcp(float x) {
#if __has_builtin(__builtin_amdgcn_rcpf)
  return __builtin_amdgcn_rcpf(x);
#else
  return 1.f / x;
#endif
}
static __device__ __forceinline__ float sigmoid_f(float x) {
  return fast_rcp(1.f + fast_exp2(-1.44269504f * x));
}
static __device__ __forceinline__ float tanh_f(float x) {
  return 1.f - 2.f * fast_rcp(1.f + fast_exp2(2.88539008f * x));
}

// Pack W_ih (768x129 f32) into [768][68] f16-pair uints in workspace (cols >=129 zero).
__global__ void convert_wih(const float* __restrict__ W_ih, unsigned int* __restrict__ w16) {
  int idx = blockIdx.x * 256 + threadIdx.x;
  if (idx >= WSZ) return;
  int j = idx / WU, c = idx - j * WU;
  int col = 2 * c;
  float f0 = (col < INn) ? W_ih[(size_t)j * INn + col] : 0.f;
  float f1 = (col + 1 < INn) ? W_ih[(size_t)j * INn + col + 1] : 0.f;
  w16[idx] = cvt2(f0, f1);
}

// ---------------- GEMM: gx[b][t][n] = x[b][t] . W_ih[n] + b_ih[n]  (f16 out) -------------
__global__ __launch_bounds__(256, 4)
void gx_gemm(const float* __restrict__ times_in, const float* __restrict__ data_in,
             const float* __restrict__ mask_in, const unsigned int* __restrict__ w16,
             const float* __restrict__ b_ih, __fp16* __restrict__ gx) {
  __shared__ __align__(16) char raw[64 * CST * 2];  // 33792 B: staging (stride AST) then C-tile (stride CST)
  __fp16* xa = (__fp16*)raw;
  __fp16* ct = (__fp16*)raw;

  const int tid = threadIdx.x;
  const int bt = blockIdx.x;
  const int b = bt >> 3, tc = bt & 7;
  const int t0 = tc * 64;
  const int n0 = blockIdx.y * 256;

  // ---- stage A: 64 rows x {data(64)|mask(64)|delta|pad} halves, f32->f16 ----
  {
    int r = tid >> 2, s = tid & 3;
    const float* src = (s < 2)
        ? data_in + ((size_t)b * Tn + t0 + r) * Vn + s * 32
        : mask_in + ((size_t)b * Tn + t0 + r) * Vn + (s - 2) * 32;
    unsigned int* dst = (unsigned int*)(xa + r * AST) + s * 16;
#pragma unroll
    for (int i = 0; i < 8; ++i) {
      float4 v = ((const float4*)src)[i];
      dst[2 * i] = cvt2(v.x, v.y);
      dst[2 * i + 1] = cvt2(v.z, v.w);
    }
  }
  if (tid < 64) {
    int g = t0 + tid;
    float tcur = times_in[(size_t)b * Tn + g];
    float d = (g < Tn - 1) ? times_in[(size_t)b * Tn + g + 1] - tcur : 0.f;
    unsigned int* p = (unsigned int*)(xa + tid * AST + 128);
    p[0] = cvt2(d, 0.f);
#pragma unroll
    for (int i = 1; i < 20; ++i) p[i] = 0u;
  }
  __syncthreads();

  const int w = tid >> 6, lane = tid & 63;
  const int m = lane & 15, q = lane >> 4;
  const int nw = n0 + w * 64;

  f32x4 acc[4][4];
#pragma unroll
  for (int i = 0; i < 4; ++i)
#pragma unroll
    for (int j = 0; j < 4; ++j) acc[i][j] = f32x4{0.f, 0.f, 0.f, 0.f};

#pragma unroll
  for (int kt = 0; kt < 5; ++kt) {
    const int k0 = kt * 32 + q * 8;
    half8_t bf[4], af[4];
#pragma unroll
    for (int nt = 0; nt < 4; ++nt) {
      int n = nw + nt * 16 + m;
      uint4 bv = *(const uint4*)(w16 + (size_t)n * WU + (k0 >> 1));
      bf[nt] = __builtin_bit_cast(half8_t, bv);
    }
#pragma unroll
    for (int mt = 0; mt < 4; ++mt) {
      uint4 av = *(const uint4*)(xa + (mt * 16 + m) * AST + k0);
      af[mt] = __builtin_bit_cast(half8_t, av);
    }
#pragma unroll
    for (int mt = 0; mt < 4; ++mt)
#pragma unroll
      for (int nt = 0; nt < 4; ++nt)
        acc[mt][nt] = __builtin_amdgcn_mfma_f32_16x16x32_f16(af[mt], bf[nt], acc[mt][nt], 0, 0, 0);
  }

  float bias[4];
#pragma unroll
  for (int nt = 0; nt < 4; ++nt) bias[nt] = b_ih[nw + nt * 16 + m];

  __syncthreads();  // staging reads done; reuse LDS as C-tile
  // C/D layout: col(n)=lane&15, row(t)=q*4+reg. Write to ct[t][n-n0], stride CST.
#pragma unroll
  for (int mt = 0; mt < 4; ++mt)
#pragma unroll
    for (int nt = 0; nt < 4; ++nt)
#pragma unroll
      for (int r = 0; r < 4; ++r)
        ct[(mt * 16 + q * 4 + r) * CST + w * 64 + nt * 16 + m] =
            (__fp16)(acc[mt][nt][r] + bias[nt]);
  __syncthreads();

  // coalesced store: thread -> row tt = tid>>2, quarter qq = tid&3 (8 uint4 each)
  {
    const int tt = tid >> 2, qq = tid & 3;
    const uint4* src = (const uint4*)(ct + tt * CST) + qq * 8;
    uint4* dst = (uint4*)(gx + ((size_t)b * Tn + t0 + tt) * 768 + n0) + qq * 8;
#pragma unroll
    for (int i = 0; i < 8; ++i) dst[i] = src[i];
  }
}

// ---------------- Scan: phase B only; (512,1) so the allocator gets a 256-VGPR budget -----
// R5 evidence: __launch_bounds__(512,2) produced a 128-arch-VGPR budget -> 192 weight uints
// landed in AGPRs -> one v_accvgpr_read per dot2 (+190 VALU/step/wave). minwaves=1 gives the
// allocator the full file (we only ever run 1 block/CU: grid == #CUs).
__global__ __launch_bounds__(512, 1)
void gru_scan2(const float* __restrict__ times_in, const float* __restrict__ W_hh,
               const float* __restrict__ b_hh, const __fp16* __restrict__ gx,
               float* __restrict__ out) {
  __shared__ __align__(16) __fp16 h_buf[2 * Hn];
  __shared__ __align__(16) float t_lds[Tn];

  const int tid = threadIdx.x;
  const int b = blockIdx.x;
  const int jg = tid >> 1;
  const int ks = tid & 1;

  t_lds[tid] = times_in[(size_t)b * Tn + tid];

  unsigned int whr[64], whz[64], whn[64];
  {
    const float* w0 = W_hh + (size_t)jg * Hn + ks * 128;
    const float* w1 = W_hh + (size_t)(jg + 256) * Hn + ks * 128;
    const float* w2 = W_hh + (size_t)(jg + 512) * Hn + ks * 128;
#pragma unroll
    for (int c = 0; c < 64; ++c) {
      whr[c] = cvt2(w0[2 * c], w0[2 * c + 1]);
      whz[c] = cvt2(w1[2 * c], w1[2 * c + 1]);
      whn[c] = cvt2(w2[2 * c], w2[2 * c + 1]);
    }
  }
  const float brh = b_hh[jg];
  const float bzh = b_hh[jg + 256];
  const float bhn = b_hh[jg + 512];

  h_buf[tid] = (__fp16)0.f;
  __syncthreads();

  const __fp16* gxb = gx + (size_t)b * Tn * 768;
  float hcur = 0.f;

  // preload step-0 gx + mask-time
  float gr = (float)gxb[jg], gz = (float)gxb[256 + jg], gn = (float)gxb[512 + jg];
  float mt = t_lds[0];

#pragma unroll 1
  for (int t = 0; t < Tn; ++t) {
    // prefetch step t+1 (global f16 + LDS time); latency hidden under this step's dots
    __fp16 pr = (__fp16)0.f, pz = (__fp16)0.f, pn = (__fp16)0.f;
    float mtn = 0.f;
    if (t + 1 < Tn) {
      const __fp16* p = gxb + (size_t)(t + 1) * 768;
      pr = p[jg]; pz = p[256 + jg]; pn = p[512 + jg];
      mtn = t_lds[t + 1];
    }

    const int cur = t & 1;
    const uint4* hb = (const uint4*)(h_buf + cur * Hn) + ks * 16;

    float sr = 0.f, sz = 0.f, shn = 0.f;
    // chunked h-broadcast: 2 uint4 in flight, rotating prefetch
    uint4 p0 = hb[0], p1 = hb[1];
#pragma unroll
    for (int cc = 0; cc < 8; ++cc) {
      uint4 q0 = p0, q1 = p1;
      if (cc < 7) { q0 = hb[2 * cc + 2]; q1 = hb[2 * cc + 3]; }
      const int cb = cc * 8;
      sr = dot2(whr[cb + 0], p0.x, sr);
      sz = dot2(whz[cb + 0], p0.x, sz);
      shn = dot2(whn[cb + 0], p0.x, shn);
      sr = dot2(whr[cb + 1], p0.y, sr);
      sz = dot2(whz[cb + 1], p0.y, sz);
      shn = dot2(whn[cb + 1], p0.y, shn);
      sr = dot2(whr[cb + 2], p0.z, sr);
      sz = dot2(whz[cb + 2], p0.z, sz);
      shn = dot2(whn[cb + 2], p0.z, shn);
      sr = dot2(whr[cb + 3], p0.w, sr);
      sz = dot2(whz[cb + 3], p0.w, sz);
      shn = dot2(whn[cb + 3], p0.w, shn);
      sr = dot2(whr[cb + 4], p1.x, sr);
      sz = dot2(whz[cb + 4], p1.x, sz);
      shn = dot2(whn[cb + 4], p1.x, shn);
      sr = dot2(whr[cb + 5], p1.y, sr);
      sz = dot2(whz[cb + 5], p1.y, sz);
      shn = dot2(whn[cb + 5], p1.y, shn);
      sr = dot2(whr[cb + 6], p1.z, sr);
      sz = dot2(whz[cb + 6], p1.z, sz);
      shn = dot2(whn[cb + 6], p1.z, shn);
      sr = dot2(whr[cb + 7], p1.w, sr);
      sz = dot2(whz[cb + 7], p1.w, sz);
      shn = dot2(whn[cb + 7], p1.w, shn);
      p0 = q0; p1 = q1;
    }

    // reduce the two k-halves on the VALU pipe (no LDS)
    sr = pair_sum(sr);
    sz = pair_sum(sz);
    shn = pair_sum(shn);

    float r = sigmoid_f(gr + sr + brh);
    float z = sigmoid_f(gz + sz + bzh);
    float n = tanh_f(gn + r * (shn + bhn));
    float hN = (1.f - z) * n + z * hcur;
    hcur = (mt > 0.f) ? hN : hcur;

    if (ks == 0) h_buf[(cur ^ 1) * Hn + jg] = (__fp16)hcur;
    __syncthreads();

    gr = (float)pr; gz = (float)pz; gn = (float)pn; mt = mtn;
  }

  if (ks == 0) out[(size_t)b * Hn + jg] = hcur;
}

// ---------------- Fallback (R3): in-kernel phase A, used only if ws too small -------------
template <bool USE_WS>
static __device__ __forceinline__ void phaseA_pass(int col, const unsigned int* __restrict__ w16,
                                                   const float* __restrict__ W_ih,
                                                   const unsigned int* x_lds, float* a) {
  const uint4* wp = (const uint4*)(w16) + (size_t)col * (WU / 4);
  const float* wf = W_ih + (size_t)col * INn;
#pragma unroll 2
  for (int kp = 0; kp < 8; ++kp) {
    uint4 wa, wb;
    if constexpr (USE_WS) {
      wa = wp[2 * kp];
      wb = wp[2 * kp + 1];
    } else {
      const float* f = wf + 16 * kp;
      wa.x = cvt2(f[0], f[1]);   wa.y = cvt2(f[2], f[3]);
      wa.z = cvt2(f[4], f[5]);   wa.w = cvt2(f[6], f[7]);
      wb.x = cvt2(f[8], f[9]);   wb.y = cvt2(f[10], f[11]);
      wb.z = cvt2(f[12], f[13]); wb.w = cvt2(f[14], f[15]);
    }
#pragma unroll
    for (int t = 0; t < Cc; ++t) {
      const uint4* xp = (const uint4*)&x_lds[t * WU + kp * 8];
      uint4 xa = xp[0], xb = xp[1];
      a[t] = dot2(wa.x, xa.x, a[t]);
      a[t] = dot2(wa.y, xa.y, a[t]);
      a[t] = dot2(wa.z, xa.z, a[t]);
      a[t] = dot2(wa.w, xa.w, a[t]);
      a[t] = dot2(wb.x, xb.x, a[t]);
      a[t] = dot2(wb.y, xb.y, a[t]);
      a[t] = dot2(wb.z, xb.z, a[t]);
      a[t] = dot2(wb.w, xb.w, a[t]);
    }
  }
  uint4 wt;
  if constexpr (USE_WS) {
    wt = wp[16];
  } else {
    wt.x = cvt2(wf[128], 0.f); wt.y = 0u; wt.z = 0u; wt.w = 0u;
  }
#pragma unroll
  for (int t = 0; t < Cc; ++t) {
    uint4 xt = *(const uint4*)&x_lds[t * WU + 64];
    a[t] = dot2(wt.x, xt.x, a[t]);
    a[t] = dot2(wt.y, xt.y, a[t]);
  }
}

template <bool USE_WS>
__global__ __launch_bounds__(512, 2)
void gru_scan_fb(const float* __restrict__ times_in, const float* __restrict__ data_in,
                 const float* __restrict__ mask_in, const unsigned int* __restrict__ w16,
                 const float* __restrict__ W_ih, const float* __restrict__ W_hh,
                 const float* __restrict__ b_ih, const float* __restrict__ b_hh,
                 float* __restrict__ out) {
  __shared__ __align__(16) float gx_lds[Cc * 768];
  __shared__ __align__(16) unsigned int x_lds[Cc * WU];
  __shared__ __align__(16) __fp16 h_buf[2 * Hn];
  __shared__ __align__(16) float t_lds[Tn];

  const int tid = threadIdx.x;
  const int b = blockIdx.x;
  const int jg = tid >> 1;
  const int ks = tid & 1;

  t_lds[tid] = times_in[(size_t)b * Tn + tid];

  unsigned int whr[64], whz[64], whn[64];
  {
    const float* w0 = W_hh + (size_t)jg * Hn + ks * 128;
    const float* w1 = W_hh + (size_t)(jg + 256) * Hn + ks * 128;
    const float* w2 = W_hh + (size_t)(jg + 512) * Hn + ks * 128;
#pragma unroll
    for (int c = 0; c < 64; ++c) {
      whr[c] = cvt2(w0[2 * c], w0[2 * c + 1]);
      whz[c] = cvt2(w1[2 * c], w1[2 * c + 1]);
      whn[c] = cvt2(w2[2 * c], w2[2 * c + 1]);
    }
  }
  const float brh = b_hh[jg];
  const float bzh = b_hh[jg + 256];
  const float bhn = b_hh[jg + 512];
  const float bi1 = b_ih[tid];
  const float bi2 = (tid < 256) ? b_ih[512 + tid] : 0.f;

  h_buf[tid] = (__fp16)0.f;
  __syncthreads();

  float hcur = 0.f;
  int cur = 0;
#pragma unroll 1
  for (int ch = 0; ch < NCH; ++ch) {
    const int t0 = ch * Cc;
    {
      int t = tid >> 6;
      int c = tid & 63;
      const float* src = (c < 32)
          ? data_in + ((size_t)b * Tn + t0 + t) * Vn + 2 * c
          : mask_in + ((size_t)b * Tn + t0 + t) * Vn + 2 * (c - 32);
      float2 v = *(const float2*)src;
      x_lds[t * WU + c] = cvt2(v.x, v.y);
      if (tid < Cc) {
        int g = t0 + tid;
        float d = (g < Tn - 1) ? (t_lds[g + 1] - t_lds[g]) : 0.f;
        uint4 tl;
        tl.x = cvt2(d, 0.f); tl.y = 0u; tl.z = 0u; tl.w = 0u;
        *(uint4*)&x_lds[tid * WU + 64] = tl;
      }
    }
    __syncthreads();
    {
      float a[Cc];
#pragma unroll
      for (int t = 0; t < Cc; ++t) a[t] = bi1;
      phaseA_pass<USE_WS>(tid, w16, W_ih, x_lds, a);
#pragma unroll
      for (int t = 0; t < Cc; ++t) gx_lds[t * 768 + tid] = a[t];
      if (tid < 256) {
#pragma unroll
        for (int t = 0; t < Cc; ++t) a[t] = bi2;
        phaseA_pass<USE_WS>(512 + tid, w16, W_ih, x_lds, a);
#pragma unroll
        for (int t = 0; t < Cc; ++t) gx_lds[t * 768 + 512 + tid] = a[t];
      }
    }
    __syncthreads();
    for (int tt = 0; tt < Cc; ++tt) {
      float sr = 0.f, sz = 0.f, shn = 0.f;
      const uint4* hb = (const uint4*)(h_buf + cur * Hn + ks * 128);
#pragma unroll
      for (int c = 0; c < 16; ++c) {
        uint4 hv = hb[c];
        sr = dot2(whr[4 * c + 0], hv.x, sr);
        sz = dot2(whz[4 * c + 0], hv.x, sz);
        shn = dot2(whn[4 * c + 0], hv.x, shn);
        sr = dot2(whr[4 * c + 1], hv.y, sr);
        sz = dot2(whz[4 * c + 1], hv.y, sz);
        shn = dot2(whn[4 * c + 1], hv.y, shn);
        sr = dot2(whr[4 * c + 2], hv.z, sr);
        sz = dot2(whz[4 * c + 2], hv.z, sz);
        shn = dot2(whn[4 * c + 2], hv.z, shn);
        sr = dot2(whr[4 * c + 3], hv.w, sr);
        sz = dot2(whz[4 * c + 3], hv.w, sz);
        shn = dot2(whn[4 * c + 3], hv.w, shn);
      }
      float gxr = gx_lds[tt * 768 + jg];
      float gxz = gx_lds[tt * 768 + 256 + jg];
      float gxn = gx_lds[tt * 768 + 512 + jg];
      sr = pair_sum(sr);
      sz = pair_sum(sz);
      shn = pair_sum(shn);
      float r = sigmoid_f(gxr + sr + brh);
      float z = sigmoid_f(gxz + sz + bzh);
      float n = tanh_f(gxn + r * (shn + bhn));
      float hN = (1.f - z) * n + z * hcur;
      hcur = (t_lds[t0 + tt] > 0.f) ? hN : hcur;
      if (ks == 0) h_buf[(cur ^ 1) * Hn + jg] = (__fp16)hcur;
      __syncthreads();
      cur ^= 1;
    }
  }
  if (ks == 0) out[(size_t)b * Hn + jg] = hcur;
}

extern "C" void kernel_launch(void* const* d_in, const int* in_sizes, int n_in,
                              void* d_out, int out_size, void* d_ws, size_t ws_size,
                              hipStream_t stream) {
  const float* times_in = (const float*)d_in[0];
  const float* data_in = (const float*)d_in[1];
  const float* mask_in = (const float*)d_in[2];
  const float* W_ih = (const float*)d_in[3];
  const float* W_hh = (const float*)d_in[4];
  const float* b_ih = (const float*)d_in[5];
  const float* b_hh = (const float*)d_in[6];
  float* out = (float*)d_out;

  unsigned int* w16 = (unsigned int*)d_ws;
  __fp16* gx = (__fp16*)((char*)d_ws + GX_OFF);

  if (ws_size >= GX_OFF + GX_BYTES) {
    hipLaunchKernelGGL(convert_wih, dim3((WSZ + 255) / 256), dim3(256), 0, stream, W_ih, w16);
    hipLaunchKernelGGL(gx_gemm, dim3(2048, 3), dim3(256), 0, stream,
                       times_in, data_in, mask_in, w16, b_ih, gx);
    hipLaunchKernelGGL(gru_scan2, dim3(Bn), dim3(512), 0, stream,
                       times_in, W_hh, b_hh, gx, out);
  } else if (ws_size >= (size_t)WSZ * 4) {
    hipLaunchKernelGGL(convert_wih, dim3((WSZ + 255) / 256), dim3(256), 0, stream, W_ih, w16);
    hipLaunchKernelGGL((gru_scan_fb<true>), dim3(Bn), dim3(512), 0, stream,
                       times_in, data_in, mask_in, w16, W_ih, W_hh, b_ih, b_hh, out);
  } else {
    hipLaunchKernelGGL((gru_scan_fb<false>), dim3(Bn), dim3(512), 0, stream,
                       times_in, data_in, mask_in, (const unsigned int*)nullptr, W_ih, W_hh,
                       b_ih, b_hh, out);
  }
}